// Round 4
// baseline (134.275 us; speedup 1.0000x reference)
//
#include <hip/hip_runtime.h>

// GCN N=100k, E=1.6M, H=64 — algebraic collapse + fixed-capacity bucket binning.
//
// Math (layer-1 input is [N,1], so each node's hidden state is a scalar function):
//   s[d] = dinv[d]*(sum_{src->d} dinv[src]*x[src] + dinv[d]*x[d])
//   relu(s*w1+b1) @ w2 = s*P^{sign(s)} + B^{sign(s)}   (P±,B± precomputed 64-vecs)
//   layer-2 scalars: a±[d], c±[d] (sign-split sums of dinv_s*s_s and dinv_s)
//   out[d] = relu(dinv[d]*(a+P+ + a-P- + c+B+ + c-B-) + b2) . wfc + bfc
//
// R4 (on top of R3's sorted-write k_place):
//   - k_init ELIMINATED: cursor-RELATIVE reservation (zero-init by one 4KB
//     hipMemsetAsync); P±/B± recomputed inside every k_bagg2 block (8 MACs/thread
//     from L2-hot w1/b1/w2 + LDS reduce — parallel, off the critical path).
//   - k_place: CHUNK 8192->4096 (391 blocks, ~1.5/CU vs 196 = half CUs idle);
//     edge stash in REGISTERS (4 named int4s, fully unrolled), so edges are read
//     from global exactly once; sorted LDS write-out kept.
//   - k_bagg2 epilogue: 64-j loop split 4-way (512 threads = 4 j-groups x 128
//     nodes) + LDS partial reduce, instead of 128/512 active lanes.
//
// Dispatches: memset -> k_place -> k_bdeg -> k_bagg1 -> k_bagg2.

#define HCH 64
#define CHUNK 4096
#define BSH 7
#define BSZ 128          // nodes per bucket
#define NBMAX 1024

__device__ __forceinline__ void lds_addf(float* p, float v) {
    __hip_atomic_fetch_add(p, v, __ATOMIC_RELAXED, __HIP_MEMORY_SCOPE_WORKGROUP);
}

// bin edges into fixed bucket regions, bucket-sorted within the chunk so the
// global write-out is a coalesced linear sweep. cursorRel is ZERO-initialized;
// absolute base = bucket*cap + rel.
__global__ __launch_bounds__(512) void k_place(const int* __restrict__ src,
                                               const int* __restrict__ dst, int e,
                                               int nb, int cap,
                                               int* __restrict__ cursorRel,
                                               int* __restrict__ ov_cursor,
                                               int* __restrict__ packed,
                                               int2* __restrict__ ovbuf) {
    __shared__ int h[NBMAX];       // counts -> placement cursor
    __shared__ int scanE[NBMAX];   // chunk-local exclusive prefix
    __shared__ int basel[NBMAX];
    __shared__ int avail[NBMAX];
    __shared__ int slpv[CHUNK];    // bucket-sorted packed values
    __shared__ short ssb[CHUNK];   // bucket id per sorted slot
    __shared__ int wsum[8];
    int t = threadIdx.x;
    for (int i = t; i < NBMAX; i += 512) h[i] = 0;
    __syncthreads();
    int cbase = blockIdx.x * CHUNK;
    int rem = min(e - cbase, CHUNK);
    int li = t * 8;
    bool fast = (li + 7 < rem);

    // ---- pass 1: load 8 edges into REGISTERS + histogram ----
    int4 sA, sB, dA, dB;
    if (fast) {
        sA = *(const int4*)(src + cbase + li);
        sB = *(const int4*)(src + cbase + li + 4);
        dA = *(const int4*)(dst + cbase + li);
        dB = *(const int4*)(dst + cbase + li + 4);
        atomicAdd(&h[dA.x >> BSH], 1); atomicAdd(&h[dA.y >> BSH], 1);
        atomicAdd(&h[dA.z >> BSH], 1); atomicAdd(&h[dA.w >> BSH], 1);
        atomicAdd(&h[dB.x >> BSH], 1); atomicAdd(&h[dB.y >> BSH], 1);
        atomicAdd(&h[dB.z >> BSH], 1); atomicAdd(&h[dB.w >> BSH], 1);
    } else {
        for (int q = li; q < rem && q < li + 8; q++)
            atomicAdd(&h[dst[cbase + q] >> BSH], 1);
    }
    __syncthreads();

    // ---- reservation (cursor-relative) + block scan over NBMAX entries ----
    int v0 = h[2 * t], v1 = h[2 * t + 1];
    for (int i = t; i < nb; i += 512) {
        int my = h[i];
        int av = 0, base = 0;
        if (my) {
            int baseRel = atomicAdd(&cursorRel[i], my);
            base = i * cap + baseRel;
            int room = cap - baseRel;
            av = room < 0 ? 0 : (room > my ? my : room);
        }
        basel[i] = base;
        avail[i] = av;
    }
    int lane = t & 63, wid = t >> 6;
    int s = v0 + v1;
    int incl = s;
#pragma unroll
    for (int d = 1; d < 64; d <<= 1) {
        int o = __shfl_up(incl, d, 64);
        if (lane >= d) incl += o;
    }
    if (lane == 63) wsum[wid] = incl;
    __syncthreads();                 // all h reads done; wsum level-1 written
    if (t < 8) {
        int v = wsum[t];
        int inc2 = v;
#pragma unroll
        for (int d = 1; d < 8; d <<= 1) {
            int o = __shfl_up(inc2, d, 8);
            if (t >= d) inc2 += o;
        }
        wsum[t] = inc2 - v;          // exclusive wave offset
    }
    for (int i = t; i < NBMAX; i += 512) h[i] = 0;  // reuse as placement cursor
    __syncthreads();
    int excl = incl - s + wsum[wid];
    scanE[2 * t] = excl;
    scanE[2 * t + 1] = excl + v0;
    __syncthreads();

    // ---- pass 2: place from registers, bucket-sorted into LDS ----
    if (fast) {
#pragma unroll
        for (int q = 0; q < 8; q++) {
            int sv = (q == 0) ? sA.x : (q == 1) ? sA.y : (q == 2) ? sA.z :
                     (q == 3) ? sA.w : (q == 4) ? sB.x : (q == 5) ? sB.y :
                     (q == 6) ? sB.z : sB.w;
            int dv = (q == 0) ? dA.x : (q == 1) ? dA.y : (q == 2) ? dA.z :
                     (q == 3) ? dA.w : (q == 4) ? dB.x : (q == 5) ? dB.y :
                     (q == 6) ? dB.z : dB.w;
            int b = dv >> BSH;
            int pos = scanE[b] + atomicAdd(&h[b], 1);
            slpv[pos] = sv | ((dv & (BSZ - 1)) << 17);
            ssb[pos] = (short)b;
        }
    } else {
        for (int q = li; q < rem && q < li + 8; q++) {
            int sv = src[cbase + q], dv = dst[cbase + q];  // L2-hot
            int b = dv >> BSH;
            int pos = scanE[b] + atomicAdd(&h[b], 1);
            slpv[pos] = sv | ((dv & (BSZ - 1)) << 17);
            ssb[pos] = (short)b;
        }
    }
    __syncthreads();

    // ---- pass 3: linear write-out (consecutive lanes -> consecutive addrs) ----
    for (int jj = t; jj < rem; jj += 512) {
        int b = ssb[jj];
        int loc = jj - scanE[b];
        int pv = slpv[jj];
        if (loc < avail[b]) {
            packed[basel[b] + loc] = pv;
        } else {
            int op = atomicAdd(ov_cursor, 1);
            ovbuf[op] = make_int2(pv & 0x1FFFF, (b << BSH) | (pv >> 17));
        }
    }
}

// per bucket: int histogram of local dst -> deg -> dinv, y = dinv*x
__global__ __launch_bounds__(512) void k_bdeg(const int* __restrict__ packed,
                                              const int* __restrict__ cursorRel,
                                              const int* __restrict__ ov_cursor,
                                              const int2* __restrict__ ovbuf,
                                              int cap, const float* __restrict__ x, int n,
                                              float* __restrict__ dinv,
                                              float* __restrict__ y) {
    __shared__ int cnt[BSZ];
    int bk = blockIdx.x, t = threadIdx.x;
    int bbase = bk * cap;
    int bcnt = min(cursorRel[bk], cap);
    if (t < BSZ) cnt[t] = 0;
    __syncthreads();
    for (int base = 0; base < bcnt; base += 2048) {
        int i0 = base + t * 4;
        if (i0 + 3 < bcnt) {
            int4 p = *(const int4*)(packed + bbase + i0);
            atomicAdd(&cnt[p.x >> 17], 1);
            atomicAdd(&cnt[p.y >> 17], 1);
            atomicAdd(&cnt[p.z >> 17], 1);
            atomicAdd(&cnt[p.w >> 17], 1);
        } else {
            for (int i = i0; i < bcnt && i < i0 + 4; i++)
                atomicAdd(&cnt[packed[bbase + i] >> 17], 1);
        }
    }
    int ovc = *ov_cursor;
    for (int i = t; i < ovc; i += 512) {
        int2 o = ovbuf[i];
        if ((o.y >> BSH) == bk) atomicAdd(&cnt[o.y & (BSZ - 1)], 1);
    }
    __syncthreads();
    int node = (bk << BSH) + t;
    if (t < BSZ && node < n) {
        float dv = rsqrtf((float)(cnt[t] + 1));  // +1 self-loop
        dinv[node] = dv;
        y[node] = dv * x[node];
    }
}

// per bucket: acc[localdst] += y[src] -> s -> val2=(dinv*s, dinv)
__global__ __launch_bounds__(512) void k_bagg1(const int* __restrict__ packed,
                                               const int* __restrict__ cursorRel,
                                               const int* __restrict__ ov_cursor,
                                               const int2* __restrict__ ovbuf,
                                               int cap,
                                               const float* __restrict__ dinv,
                                               const float* __restrict__ y, int n,
                                               float2* __restrict__ val2) {
    __shared__ float acc[BSZ];
    int bk = blockIdx.x, t = threadIdx.x;
    int bbase = bk * cap;
    int bcnt = min(cursorRel[bk], cap);
    if (t < BSZ) acc[t] = 0.f;
    __syncthreads();
    for (int base = 0; base < bcnt; base += 2048) {
        int i0 = base + t * 4;
        if (i0 + 3 < bcnt) {
            int4 p = *(const int4*)(packed + bbase + i0);
            float y0 = y[p.x & 0x1FFFF], y1 = y[p.y & 0x1FFFF];
            float y2 = y[p.z & 0x1FFFF], y3 = y[p.w & 0x1FFFF];
            lds_addf(&acc[p.x >> 17], y0);
            lds_addf(&acc[p.y >> 17], y1);
            lds_addf(&acc[p.z >> 17], y2);
            lds_addf(&acc[p.w >> 17], y3);
        } else {
            for (int i = i0; i < bcnt && i < i0 + 4; i++) {
                int p = packed[bbase + i];
                lds_addf(&acc[p >> 17], y[p & 0x1FFFF]);
            }
        }
    }
    int ovc = *ov_cursor;
    for (int i = t; i < ovc; i += 512) {
        int2 o = ovbuf[i];
        if ((o.y >> BSH) == bk) lds_addf(&acc[o.y & (BSZ - 1)], y[o.x]);
    }
    __syncthreads();
    int node = (bk << BSH) + t;
    if (t < BSZ && node < n) {
        float dv = dinv[node];
        float s = dv * (acc[t] + y[node]);  // y[node] = dv*x[node]
        val2[node] = make_float2(dv * s, dv);
    }
}

// per bucket: sign-split accumulate of val2[src] + fused epilogue -> out.
// P±/B± recomputed per block from w1/b1/w2 (L2-hot, parallel with nothing on
// the critical path); epilogue parallelized 4-way over j.
__global__ __launch_bounds__(512) void k_bagg2(const int* __restrict__ packed,
                                               const int* __restrict__ cursorRel,
                                               const int* __restrict__ ov_cursor,
                                               const int2* __restrict__ ovbuf,
                                               int cap, const float2* __restrict__ val2,
                                               const float* __restrict__ dinv,
                                               const float* __restrict__ w1,
                                               const float* __restrict__ b1,
                                               const float* __restrict__ w2,
                                               const float* __restrict__ b2,
                                               const float* __restrict__ wfc,
                                               const float* __restrict__ bfc,
                                               float* __restrict__ out, int n) {
    __shared__ float aa[2 * BSZ];   // [0..BSZ): positive, [BSZ..2BSZ): negative
    __shared__ float cc[2 * BSZ];
    __shared__ float part[8][4][HCH];   // P-compute partials
    __shared__ float sP[4 * HCH], sb2[HCH], swfc[HCH];
    __shared__ float part2[4][BSZ];     // epilogue partials
    __shared__ float fsum;
    int bk = blockIdx.x, t = threadIdx.x;
    int bbase = bk * cap;
    int bcnt = min(cursorRel[bk], cap);

    // --- stage A: P partials (regs->LDS), zero aa/cc, load sb2/swfc ---
    {
        int j = t & 63, seg = t >> 6;
        float pp = 0.f, pm = 0.f, bp = 0.f, bm = 0.f;
#pragma unroll
        for (int kk = 0; kk < 8; kk++) {
            int k = seg * 8 + kk;
            float w = w1[k], b = b1[k], v = w2[k * HCH + j];
            if (w > 0.f) { pp += w * v; bp += b * v; }
            else if (w < 0.f) { pm += w * v; bm += b * v; }
            else { float rb = b > 0.f ? b : 0.f; bp += rb * v; bm += rb * v; }
        }
        part[seg][0][j] = pp; part[seg][1][j] = pm;
        part[seg][2][j] = bp; part[seg][3][j] = bm;
    }
    if (t < 256) aa[t] = 0.f; else cc[t - 256] = 0.f;
    if (t >= 256 && t < 320) sb2[t - 256] = b2[t - 256];
    if (t >= 320 && t < 384) swfc[t - 320] = wfc[t - 320];
    if (t == 448) fsum = 0.f;
    __syncthreads();
    // --- stage B: reduce partials -> sP; |B| sum -> fsum ---
    if (t < 4 * HCH) {
        int c = t >> 6, jj = t & 63;
        float ssum = 0.f;
#pragma unroll
        for (int g = 0; g < 8; g++) ssum += part[g][c][jj];
        sP[t] = ssum;
        if (c >= 2) lds_addf(&fsum, fabsf(ssum));
    }
    __syncthreads();
    bool useB = fsum != 0.f;

    // --- stage C: edge accumulation ---
    for (int base = 0; base < bcnt; base += 2048) {
        int i0 = base + t * 4;
        if (i0 + 3 < bcnt) {
            int4 p = *(const int4*)(packed + bbase + i0);
            float2 v0 = val2[p.x & 0x1FFFF], v1 = val2[p.y & 0x1FFFF];
            float2 v2 = val2[p.z & 0x1FFFF], v3 = val2[p.w & 0x1FFFF];
            int o0 = (v0.x > 0.f ? 0 : BSZ) + (p.x >> 17);
            int o1 = (v1.x > 0.f ? 0 : BSZ) + (p.y >> 17);
            int o2 = (v2.x > 0.f ? 0 : BSZ) + (p.z >> 17);
            int o3 = (v3.x > 0.f ? 0 : BSZ) + (p.w >> 17);
            lds_addf(&aa[o0], v0.x); lds_addf(&aa[o1], v1.x);
            lds_addf(&aa[o2], v2.x); lds_addf(&aa[o3], v3.x);
            if (useB) {
                lds_addf(&cc[o0], v0.y); lds_addf(&cc[o1], v1.y);
                lds_addf(&cc[o2], v2.y); lds_addf(&cc[o3], v3.y);
            }
        } else {
            for (int i = i0; i < bcnt && i < i0 + 4; i++) {
                int p = packed[bbase + i];
                float2 v = val2[p & 0x1FFFF];
                int off = (v.x > 0.f ? 0 : BSZ) + (p >> 17);
                lds_addf(&aa[off], v.x);
                if (useB) lds_addf(&cc[off], v.y);
            }
        }
    }
    int ovc = *ov_cursor;
    for (int i = t; i < ovc; i += 512) {
        int2 o = ovbuf[i];
        if ((o.y >> BSH) == bk) {
            float2 v = val2[o.x];
            int off = (v.x > 0.f ? 0 : BSZ) + (o.y & (BSZ - 1));
            lds_addf(&aa[off], v.x);
            if (useB) lds_addf(&cc[off], v.y);
        }
    }
    __syncthreads();

    // --- stage D: epilogue, 4-way parallel over j (q = t>>7 handles 16 j's) ---
    int tt = t & (BSZ - 1), q = t >> 7;
    int node = (bk << BSH) + tt;
    if (node < n) {
        float a_p = aa[tt], a_m = aa[BSZ + tt];
        float c_p = cc[tt], c_m = cc[BSZ + tt];
        float2 sv = val2[node];  // self-loop
        if (sv.x > 0.f) { a_p += sv.x; c_p += sv.y; }
        else            { a_m += sv.x; c_m += sv.y; }
        float dv = dinv[node];
        float pacc = 0.f;
#pragma unroll
        for (int u = 0; u < 16; u++) {
            int j = q * 16 + u;
            float z = dv * (a_p * sP[j] + a_m * sP[HCH + j] +
                            c_p * sP[2 * HCH + j] + c_m * sP[3 * HCH + j]) + sb2[j];
            z = z > 0.f ? z : 0.f;
            pacc += z * swfc[j];
        }
        part2[q][tt] = pacc;
    }
    __syncthreads();
    if (t < BSZ) {
        int nd = (bk << BSH) + t;
        if (nd < n)
            out[nd] = part2[0][t] + part2[1][t] + part2[2][t] + part2[3][t] + bfc[0];
    }
}

extern "C" void kernel_launch(void* const* d_in, const int* in_sizes, int n_in,
                              void* d_out, int out_size, void* d_ws, size_t ws_size,
                              hipStream_t stream) {
    const float* x   = (const float*)d_in[0];
    const int*   ei  = (const int*)d_in[1];
    const float* w1  = (const float*)d_in[2];
    const float* b1  = (const float*)d_in[3];
    const float* w2  = (const float*)d_in[4];
    const float* b2  = (const float*)d_in[5];
    const float* wfc = (const float*)d_in[6];
    const float* bfc = (const float*)d_in[7];
    float* out = (float*)d_out;

    const int n = in_sizes[0];      // 100000
    const int e = in_sizes[1] / 2;  // 1600000
    const int* src = ei;
    const int* dst = ei + e;

    const int nb = (n + BSZ - 1) >> BSH;          // 782 buckets
    int avg = (e + nb - 1) / nb;                  // ~2047
    int cap = ((avg + avg / 4 + 64) + 15) & ~15;  // ~13 sigma headroom, 16-aligned

    auto al = [](size_t v) { return (v + 255) & ~(size_t)255; };
    char* ws = (char*)d_ws;
    size_t o = 0;
    int* cursorRel = (int*)(ws + o);  o = al(o + (size_t)NBMAX * 4);   // at ws+0
    int* ov_cursor = (int*)(ws + o);  o = al(o + 256);                 // at ws+4096
    float* dinv  = (float*)(ws + o);  o = al(o + (size_t)n * 4);
    float* y     = (float*)(ws + o);  o = al(o + (size_t)n * 4);
    float2* val2 = (float2*)(ws + o); o = al(o + (size_t)n * 8);
    int* packed  = (int*)(ws + o);    o = al(o + (size_t)nb * cap * 4);
    int2* ovbuf  = (int2*)(ws + o);   o = al(o + (size_t)e * 8);
    (void)ws_size;

    const int nchunk = (e + CHUNK - 1) / CHUNK;  // 391 chunks

    // zero cursorRel[NBMAX] + ov_cursor (contiguous from ws+0)
    hipMemsetAsync(ws, 0, (size_t)NBMAX * 4 + 4, stream);
    k_place<<<nchunk, 512, 0, stream>>>(src, dst, e, nb, cap, cursorRel, ov_cursor,
                                        packed, ovbuf);
    k_bdeg<<<nb, 512, 0, stream>>>(packed, cursorRel, ov_cursor, ovbuf, cap, x, n,
                                   dinv, y);
    k_bagg1<<<nb, 512, 0, stream>>>(packed, cursorRel, ov_cursor, ovbuf, cap, dinv, y,
                                    n, val2);
    k_bagg2<<<nb, 512, 0, stream>>>(packed, cursorRel, ov_cursor, ovbuf, cap, val2,
                                    dinv, w1, b1, w2, b2, wfc, bfc, out, n);
}

// Round 5
// 132.967 us; speedup vs baseline: 1.0098x; 1.0098x over previous
//
#include <hip/hip_runtime.h>

// GCN N=100k, E=1.6M, H=64 — algebraic collapse + fixed-capacity bucket binning.
//
// Math (layer-1 input is [N,1], so each node's hidden state is a scalar function):
//   s[d] = dinv[d]*(sum_{src->d} dinv[src]*x[src] + dinv[d]*x[d])
//   relu(s*w1+b1) @ w2 = s*P^{sign(s)} + B^{sign(s)}   (P±,B± precomputed 64-vecs)
//   layer-2 scalars: a±[d], c±[d] (sign-split sums of dinv_s*s_s and dinv_s)
//   out[d] = relu(dinv[d]*(a+P+ + a-P- + c+B+ + c-B-) + b2) . wfc + bfc
//
// R5 = R3's k_place geometry (CHUNK=8192: 196 blocks, half the reservation
// atomics of 4096, 10.5-edge avg sorted write runs) + R4's keepers:
//   - edge stash in REGISTERS (16 edges/thread, unrolled constant-indexed
//     arrays -> VGPRs), edges read from global exactly once;
//   - no k_init: cursor-RELATIVE reservation, zeroed by one 4KB hipMemsetAsync;
//     P±/B± recomputed per k_bagg2 block (L2-hot w1/b1/w2, off critical path);
//   - k_bagg2 epilogue 4-way parallel over j + LDS partial reduce.
//
// Dispatches: memset -> k_place -> k_bdeg -> k_bagg1 -> k_bagg2.

#define HCH 64
#define CHUNK 8192
#define BSH 7
#define BSZ 128          // nodes per bucket
#define NBMAX 1024

__device__ __forceinline__ void lds_addf(float* p, float v) {
    __hip_atomic_fetch_add(p, v, __ATOMIC_RELAXED, __HIP_MEMORY_SCOPE_WORKGROUP);
}

// bin edges into fixed bucket regions, bucket-sorted within the chunk so the
// global write-out is a coalesced linear sweep. cursorRel is ZERO-initialized;
// absolute base = bucket*cap + rel.
__global__ __launch_bounds__(512) void k_place(const int* __restrict__ src,
                                               const int* __restrict__ dst, int e,
                                               int nb, int cap,
                                               int* __restrict__ cursorRel,
                                               int* __restrict__ ov_cursor,
                                               int* __restrict__ packed,
                                               int2* __restrict__ ovbuf) {
    __shared__ int h[NBMAX];       // counts -> placement cursor
    __shared__ int scanE[NBMAX];   // chunk-local exclusive prefix
    __shared__ int basel[NBMAX];
    __shared__ int avail[NBMAX];
    __shared__ int slpv[CHUNK];    // bucket-sorted packed values
    __shared__ short ssb[CHUNK];   // bucket id per sorted slot
    __shared__ int wsum[8];
    int t = threadIdx.x;
    for (int i = t; i < NBMAX; i += 512) h[i] = 0;
    __syncthreads();
    int cbase = blockIdx.x * CHUNK;
    int rem = min(e - cbase, CHUNK);
    int li = t * 16;
    bool fast = (li + 15 < rem);

    // ---- pass 1: load 16 edges into REGISTERS + histogram ----
    int svr[16], dvr[16];
    if (fast) {
        int4 sA = *(const int4*)(src + cbase + li);
        int4 sB = *(const int4*)(src + cbase + li + 4);
        int4 sC = *(const int4*)(src + cbase + li + 8);
        int4 sD = *(const int4*)(src + cbase + li + 12);
        int4 dA = *(const int4*)(dst + cbase + li);
        int4 dB = *(const int4*)(dst + cbase + li + 4);
        int4 dC = *(const int4*)(dst + cbase + li + 8);
        int4 dD = *(const int4*)(dst + cbase + li + 12);
        svr[0] = sA.x; svr[1] = sA.y; svr[2] = sA.z; svr[3] = sA.w;
        svr[4] = sB.x; svr[5] = sB.y; svr[6] = sB.z; svr[7] = sB.w;
        svr[8] = sC.x; svr[9] = sC.y; svr[10] = sC.z; svr[11] = sC.w;
        svr[12] = sD.x; svr[13] = sD.y; svr[14] = sD.z; svr[15] = sD.w;
        dvr[0] = dA.x; dvr[1] = dA.y; dvr[2] = dA.z; dvr[3] = dA.w;
        dvr[4] = dB.x; dvr[5] = dB.y; dvr[6] = dB.z; dvr[7] = dB.w;
        dvr[8] = dC.x; dvr[9] = dC.y; dvr[10] = dC.z; dvr[11] = dC.w;
        dvr[12] = dD.x; dvr[13] = dD.y; dvr[14] = dD.z; dvr[15] = dD.w;
#pragma unroll
        for (int q = 0; q < 16; q++) atomicAdd(&h[dvr[q] >> BSH], 1);
    } else {
        for (int q = li; q < rem && q < li + 16; q++)
            atomicAdd(&h[dst[cbase + q] >> BSH], 1);
    }
    __syncthreads();

    // ---- reservation (cursor-relative) + block scan over NBMAX entries ----
    int v0 = h[2 * t], v1 = h[2 * t + 1];
    for (int i = t; i < nb; i += 512) {
        int my = h[i];
        int av = 0, base = 0;
        if (my) {
            int baseRel = atomicAdd(&cursorRel[i], my);
            base = i * cap + baseRel;
            int room = cap - baseRel;
            av = room < 0 ? 0 : (room > my ? my : room);
        }
        basel[i] = base;
        avail[i] = av;
    }
    int lane = t & 63, wid = t >> 6;
    int s = v0 + v1;
    int incl = s;
#pragma unroll
    for (int d = 1; d < 64; d <<= 1) {
        int o = __shfl_up(incl, d, 64);
        if (lane >= d) incl += o;
    }
    if (lane == 63) wsum[wid] = incl;
    __syncthreads();                 // all h reads done; wsum level-1 written
    if (t < 8) {
        int v = wsum[t];
        int inc2 = v;
#pragma unroll
        for (int d = 1; d < 8; d <<= 1) {
            int o = __shfl_up(inc2, d, 8);
            if (t >= d) inc2 += o;
        }
        wsum[t] = inc2 - v;          // exclusive wave offset
    }
    for (int i = t; i < NBMAX; i += 512) h[i] = 0;  // reuse as placement cursor
    __syncthreads();
    int excl = incl - s + wsum[wid];
    scanE[2 * t] = excl;
    scanE[2 * t + 1] = excl + v0;
    __syncthreads();

    // ---- pass 2: place from registers, bucket-sorted into LDS ----
    if (fast) {
#pragma unroll
        for (int q = 0; q < 16; q++) {
            int sv = svr[q], dv = dvr[q];
            int b = dv >> BSH;
            int pos = scanE[b] + atomicAdd(&h[b], 1);
            slpv[pos] = sv | ((dv & (BSZ - 1)) << 17);
            ssb[pos] = (short)b;
        }
    } else {
        for (int q = li; q < rem && q < li + 16; q++) {
            int sv = src[cbase + q], dv = dst[cbase + q];  // L2-hot
            int b = dv >> BSH;
            int pos = scanE[b] + atomicAdd(&h[b], 1);
            slpv[pos] = sv | ((dv & (BSZ - 1)) << 17);
            ssb[pos] = (short)b;
        }
    }
    __syncthreads();

    // ---- pass 3: linear write-out (consecutive lanes -> consecutive addrs) ----
    for (int jj = t; jj < rem; jj += 512) {
        int b = ssb[jj];
        int loc = jj - scanE[b];
        int pv = slpv[jj];
        if (loc < avail[b]) {
            packed[basel[b] + loc] = pv;
        } else {
            int op = atomicAdd(ov_cursor, 1);
            ovbuf[op] = make_int2(pv & 0x1FFFF, (b << BSH) | (pv >> 17));
        }
    }
}

// per bucket: int histogram of local dst -> deg -> dinv, y = dinv*x
__global__ __launch_bounds__(512) void k_bdeg(const int* __restrict__ packed,
                                              const int* __restrict__ cursorRel,
                                              const int* __restrict__ ov_cursor,
                                              const int2* __restrict__ ovbuf,
                                              int cap, const float* __restrict__ x, int n,
                                              float* __restrict__ dinv,
                                              float* __restrict__ y) {
    __shared__ int cnt[BSZ];
    int bk = blockIdx.x, t = threadIdx.x;
    int bbase = bk * cap;
    int bcnt = min(cursorRel[bk], cap);
    if (t < BSZ) cnt[t] = 0;
    __syncthreads();
    for (int base = 0; base < bcnt; base += 2048) {
        int i0 = base + t * 4;
        if (i0 + 3 < bcnt) {
            int4 p = *(const int4*)(packed + bbase + i0);
            atomicAdd(&cnt[p.x >> 17], 1);
            atomicAdd(&cnt[p.y >> 17], 1);
            atomicAdd(&cnt[p.z >> 17], 1);
            atomicAdd(&cnt[p.w >> 17], 1);
        } else {
            for (int i = i0; i < bcnt && i < i0 + 4; i++)
                atomicAdd(&cnt[packed[bbase + i] >> 17], 1);
        }
    }
    int ovc = *ov_cursor;
    for (int i = t; i < ovc; i += 512) {
        int2 o = ovbuf[i];
        if ((o.y >> BSH) == bk) atomicAdd(&cnt[o.y & (BSZ - 1)], 1);
    }
    __syncthreads();
    int node = (bk << BSH) + t;
    if (t < BSZ && node < n) {
        float dv = rsqrtf((float)(cnt[t] + 1));  // +1 self-loop
        dinv[node] = dv;
        y[node] = dv * x[node];
    }
}

// per bucket: acc[localdst] += y[src] -> s -> val2=(dinv*s, dinv)
__global__ __launch_bounds__(512) void k_bagg1(const int* __restrict__ packed,
                                               const int* __restrict__ cursorRel,
                                               const int* __restrict__ ov_cursor,
                                               const int2* __restrict__ ovbuf,
                                               int cap,
                                               const float* __restrict__ dinv,
                                               const float* __restrict__ y, int n,
                                               float2* __restrict__ val2) {
    __shared__ float acc[BSZ];
    int bk = blockIdx.x, t = threadIdx.x;
    int bbase = bk * cap;
    int bcnt = min(cursorRel[bk], cap);
    if (t < BSZ) acc[t] = 0.f;
    __syncthreads();
    for (int base = 0; base < bcnt; base += 2048) {
        int i0 = base + t * 4;
        if (i0 + 3 < bcnt) {
            int4 p = *(const int4*)(packed + bbase + i0);
            float y0 = y[p.x & 0x1FFFF], y1 = y[p.y & 0x1FFFF];
            float y2 = y[p.z & 0x1FFFF], y3 = y[p.w & 0x1FFFF];
            lds_addf(&acc[p.x >> 17], y0);
            lds_addf(&acc[p.y >> 17], y1);
            lds_addf(&acc[p.z >> 17], y2);
            lds_addf(&acc[p.w >> 17], y3);
        } else {
            for (int i = i0; i < bcnt && i < i0 + 4; i++) {
                int p = packed[bbase + i];
                lds_addf(&acc[p >> 17], y[p & 0x1FFFF]);
            }
        }
    }
    int ovc = *ov_cursor;
    for (int i = t; i < ovc; i += 512) {
        int2 o = ovbuf[i];
        if ((o.y >> BSH) == bk) lds_addf(&acc[o.y & (BSZ - 1)], y[o.x]);
    }
    __syncthreads();
    int node = (bk << BSH) + t;
    if (t < BSZ && node < n) {
        float dv = dinv[node];
        float s = dv * (acc[t] + y[node]);  // y[node] = dv*x[node]
        val2[node] = make_float2(dv * s, dv);
    }
}

// per bucket: sign-split accumulate of val2[src] + fused epilogue -> out.
// P±/B± recomputed per block from w1/b1/w2 (L2-hot, off the critical path);
// epilogue parallelized 4-way over j.
__global__ __launch_bounds__(512) void k_bagg2(const int* __restrict__ packed,
                                               const int* __restrict__ cursorRel,
                                               const int* __restrict__ ov_cursor,
                                               const int2* __restrict__ ovbuf,
                                               int cap, const float2* __restrict__ val2,
                                               const float* __restrict__ dinv,
                                               const float* __restrict__ w1,
                                               const float* __restrict__ b1,
                                               const float* __restrict__ w2,
                                               const float* __restrict__ b2,
                                               const float* __restrict__ wfc,
                                               const float* __restrict__ bfc,
                                               float* __restrict__ out, int n) {
    __shared__ float aa[2 * BSZ];   // [0..BSZ): positive, [BSZ..2BSZ): negative
    __shared__ float cc[2 * BSZ];
    __shared__ float part[8][4][HCH];   // P-compute partials
    __shared__ float sP[4 * HCH], sb2[HCH], swfc[HCH];
    __shared__ float part2[4][BSZ];     // epilogue partials
    __shared__ float fsum;
    int bk = blockIdx.x, t = threadIdx.x;
    int bbase = bk * cap;
    int bcnt = min(cursorRel[bk], cap);

    // --- stage A: P partials (regs->LDS), zero aa/cc, load sb2/swfc ---
    {
        int j = t & 63, seg = t >> 6;
        float pp = 0.f, pm = 0.f, bp = 0.f, bm = 0.f;
#pragma unroll
        for (int kk = 0; kk < 8; kk++) {
            int k = seg * 8 + kk;
            float w = w1[k], b = b1[k], v = w2[k * HCH + j];
            if (w > 0.f) { pp += w * v; bp += b * v; }
            else if (w < 0.f) { pm += w * v; bm += b * v; }
            else { float rb = b > 0.f ? b : 0.f; bp += rb * v; bm += rb * v; }
        }
        part[seg][0][j] = pp; part[seg][1][j] = pm;
        part[seg][2][j] = bp; part[seg][3][j] = bm;
    }
    if (t < 256) aa[t] = 0.f; else cc[t - 256] = 0.f;
    if (t >= 256 && t < 320) sb2[t - 256] = b2[t - 256];
    if (t >= 320 && t < 384) swfc[t - 320] = wfc[t - 320];
    if (t == 448) fsum = 0.f;
    __syncthreads();
    // --- stage B: reduce partials -> sP; |B| sum -> fsum ---
    if (t < 4 * HCH) {
        int c = t >> 6, jj = t & 63;
        float ssum = 0.f;
#pragma unroll
        for (int g = 0; g < 8; g++) ssum += part[g][c][jj];
        sP[t] = ssum;
        if (c >= 2) lds_addf(&fsum, fabsf(ssum));
    }
    __syncthreads();
    bool useB = fsum != 0.f;

    // --- stage C: edge accumulation ---
    for (int base = 0; base < bcnt; base += 2048) {
        int i0 = base + t * 4;
        if (i0 + 3 < bcnt) {
            int4 p = *(const int4*)(packed + bbase + i0);
            float2 v0 = val2[p.x & 0x1FFFF], v1 = val2[p.y & 0x1FFFF];
            float2 v2 = val2[p.z & 0x1FFFF], v3 = val2[p.w & 0x1FFFF];
            int o0 = (v0.x > 0.f ? 0 : BSZ) + (p.x >> 17);
            int o1 = (v1.x > 0.f ? 0 : BSZ) + (p.y >> 17);
            int o2 = (v2.x > 0.f ? 0 : BSZ) + (p.z >> 17);
            int o3 = (v3.x > 0.f ? 0 : BSZ) + (p.w >> 17);
            lds_addf(&aa[o0], v0.x); lds_addf(&aa[o1], v1.x);
            lds_addf(&aa[o2], v2.x); lds_addf(&aa[o3], v3.x);
            if (useB) {
                lds_addf(&cc[o0], v0.y); lds_addf(&cc[o1], v1.y);
                lds_addf(&cc[o2], v2.y); lds_addf(&cc[o3], v3.y);
            }
        } else {
            for (int i = i0; i < bcnt && i < i0 + 4; i++) {
                int p = packed[bbase + i];
                float2 v = val2[p & 0x1FFFF];
                int off = (v.x > 0.f ? 0 : BSZ) + (p >> 17);
                lds_addf(&aa[off], v.x);
                if (useB) lds_addf(&cc[off], v.y);
            }
        }
    }
    int ovc = *ov_cursor;
    for (int i = t; i < ovc; i += 512) {
        int2 o = ovbuf[i];
        if ((o.y >> BSH) == bk) {
            float2 v = val2[o.x];
            int off = (v.x > 0.f ? 0 : BSZ) + (o.y & (BSZ - 1));
            lds_addf(&aa[off], v.x);
            if (useB) lds_addf(&cc[off], v.y);
        }
    }
    __syncthreads();

    // --- stage D: epilogue, 4-way parallel over j (q = t>>7 handles 16 j's) ---
    int tt = t & (BSZ - 1), q = t >> 7;
    int node = (bk << BSH) + tt;
    if (node < n) {
        float a_p = aa[tt], a_m = aa[BSZ + tt];
        float c_p = cc[tt], c_m = cc[BSZ + tt];
        float2 sv = val2[node];  // self-loop
        if (sv.x > 0.f) { a_p += sv.x; c_p += sv.y; }
        else            { a_m += sv.x; c_m += sv.y; }
        float dv = dinv[node];
        float pacc = 0.f;
#pragma unroll
        for (int u = 0; u < 16; u++) {
            int j = q * 16 + u;
            float z = dv * (a_p * sP[j] + a_m * sP[HCH + j] +
                            c_p * sP[2 * HCH + j] + c_m * sP[3 * HCH + j]) + sb2[j];
            z = z > 0.f ? z : 0.f;
            pacc += z * swfc[j];
        }
        part2[q][tt] = pacc;
    }
    __syncthreads();
    if (t < BSZ) {
        int nd = (bk << BSH) + t;
        if (nd < n)
            out[nd] = part2[0][t] + part2[1][t] + part2[2][t] + part2[3][t] + bfc[0];
    }
}

extern "C" void kernel_launch(void* const* d_in, const int* in_sizes, int n_in,
                              void* d_out, int out_size, void* d_ws, size_t ws_size,
                              hipStream_t stream) {
    const float* x   = (const float*)d_in[0];
    const int*   ei  = (const int*)d_in[1];
    const float* w1  = (const float*)d_in[2];
    const float* b1  = (const float*)d_in[3];
    const float* w2  = (const float*)d_in[4];
    const float* b2  = (const float*)d_in[5];
    const float* wfc = (const float*)d_in[6];
    const float* bfc = (const float*)d_in[7];
    float* out = (float*)d_out;

    const int n = in_sizes[0];      // 100000
    const int e = in_sizes[1] / 2;  // 1600000
    const int* src = ei;
    const int* dst = ei + e;

    const int nb = (n + BSZ - 1) >> BSH;          // 782 buckets
    int avg = (e + nb - 1) / nb;                  // ~2047
    int cap = ((avg + avg / 4 + 64) + 15) & ~15;  // ~13 sigma headroom, 16-aligned

    auto al = [](size_t v) { return (v + 255) & ~(size_t)255; };
    char* ws = (char*)d_ws;
    size_t o = 0;
    int* cursorRel = (int*)(ws + o);  o = al(o + (size_t)NBMAX * 4);   // at ws+0
    int* ov_cursor = (int*)(ws + o);  o = al(o + 256);                 // at ws+4096
    float* dinv  = (float*)(ws + o);  o = al(o + (size_t)n * 4);
    float* y     = (float*)(ws + o);  o = al(o + (size_t)n * 4);
    float2* val2 = (float2*)(ws + o); o = al(o + (size_t)n * 8);
    int* packed  = (int*)(ws + o);    o = al(o + (size_t)nb * cap * 4);
    int2* ovbuf  = (int2*)(ws + o);   o = al(o + (size_t)e * 8);
    (void)ws_size;

    const int nchunk = (e + CHUNK - 1) / CHUNK;  // 196 chunks

    // zero cursorRel[NBMAX] + ov_cursor (contiguous from ws+0)
    hipMemsetAsync(ws, 0, (size_t)NBMAX * 4 + 4, stream);
    k_place<<<nchunk, 512, 0, stream>>>(src, dst, e, nb, cap, cursorRel, ov_cursor,
                                        packed, ovbuf);
    k_bdeg<<<nb, 512, 0, stream>>>(packed, cursorRel, ov_cursor, ovbuf, cap, x, n,
                                   dinv, y);
    k_bagg1<<<nb, 512, 0, stream>>>(packed, cursorRel, ov_cursor, ovbuf, cap, dinv, y,
                                    n, val2);
    k_bagg2<<<nb, 512, 0, stream>>>(packed, cursorRel, ov_cursor, ovbuf, cap, val2,
                                    dinv, w1, b1, w2, b2, wfc, bfc, out, n);
}